// Round 13
// baseline (64.785 us; speedup 1.0000x reference)
//
#include <hip/hip_runtime.h>

#define FDIM   251
#define NFILT  80
#define KPAD   256        // K padded to 8 chunks of 32 (zeros past 250)
#define T_IN   64000
#define T_OUT  63750      // 64000 - 251 + 1
#define NCHUNK 1024       // output positions per block
#define NFT    5          // filter tiles (16 filters each)
#define CPYLEN 648        // dwords per shifted copy; 648 % 32 == 8 -> bank stagger
#define XSTOT  (8 * CPYLEN)
#define TS     516        // LDS out-tile row stride (dwords): 512 + 4 pad

typedef short bf16x8 __attribute__((ext_vector_type(8)));
typedef float f32x4  __attribute__((ext_vector_type(4)));

__device__ __forceinline__ unsigned short f2bf(float f) {
  unsigned int u = __float_as_uint(f);
  unsigned int r = (u + 0x7fffu + ((u >> 16) & 1u)) >> 16;   // RNE
  return (unsigned short)r;
}
__device__ __forceinline__ unsigned int packbf(float a, float b) {
  return (unsigned int)f2bf(a) | ((unsigned int)f2bf(b) << 16);
}

// ---------------------------------------------------------------------------
// Filter construction (validated rounds 1-12). Emits bf16 W[80][256].
// ---------------------------------------------------------------------------
__device__ __forceinline__ void norm_pm1_shared(float* a, float* scratch, int tid) {
  float v  = (tid < FDIM) ? a[tid] : 0.f;
  float mn = (tid < FDIM) ? v : 1e30f;
  float mx = (tid < FDIM) ? v : -1e30f;
  #pragma unroll
  for (int o = 32; o > 0; o >>= 1) {
    mn = fminf(mn, __shfl_down(mn, o));
    mx = fmaxf(mx, __shfl_down(mx, o));
  }
  const int wid = tid >> 6;
  if ((tid & 63) == 0) { scratch[wid] = mn; scratch[4 + wid] = mx; }
  __syncthreads();
  if (tid == 0) {
    scratch[0] = fminf(fminf(scratch[0], scratch[1]), fminf(scratch[2], scratch[3]));
    scratch[4] = fmaxf(fmaxf(scratch[4], scratch[5]), fmaxf(scratch[6], scratch[7]));
  }
  __syncthreads();
  const float gmn = scratch[0], gmx = scratch[4];
  const float nv = 2.f * (v - gmn) / (gmx - gmn + 1e-6f) - 1.f;
  __syncthreads();
  float s = (tid < FDIM) ? nv : 0.f;
  #pragma unroll
  for (int o = 32; o > 0; o >>= 1) s += __shfl_down(s, o);
  if ((tid & 63) == 0) scratch[wid] = s;
  __syncthreads();
  if (tid == 0) scratch[0] = (scratch[0] + scratch[1] + scratch[2] + scratch[3]) / 251.f;
  __syncthreads();
  const float mean = scratch[0];
  if (tid < FDIM) a[tid] = nv - mean;
  __syncthreads();
}

__global__ __launch_bounds__(256) void build_filters_kernel(
    const float* __restrict__ nf1, const float* __restrict__ nf2,
    const float* __restrict__ nf3, const float* __restrict__ nf4,
    const float* __restrict__ amp1, const float* __restrict__ amp2,
    unsigned short* __restrict__ Wbf) {
  __shared__ float ir1[FDIM], ir2[FDIM], casc[FDIM];
  __shared__ float scratch[8];
  const int f = blockIdx.x, tid = threadIdx.x;
  const float FS  = 16000.f;
  const float MF  = 50.f / 16000.f;
  const float PIF = 3.14159265358979323846f;
  const float TPI = 6.28318530717958647692f;

  const float f1 = fminf(fmaxf(fabsf(nf1[f]) + MF, 0.f), 0.5f);
  const float f2 = fminf(fmaxf(f1 + fabsf(nf2[f] - f1) + MF, 0.f), 0.5f);
  const float f3 = fminf(fmaxf(fabsf(nf3[f]) + MF, 0.f), 0.5f);
  const float f4 = fminf(fmaxf(f3 + fabsf(nf4[f] - f3) + MF, 0.f), 0.5f);
  const float a1 = fabsf(amp1[f]);
  const float a2 = fabsf(amp2[f]);

  if (tid < FDIM) {
    const float t = (float)(tid + 1) / FS;
    {
      const float fcs = 0.5f * (f1 + f2) * FS, bws = (f2 - f1) * FS;
      const float pb = PIF * bws;
      ir1[tid] = a1 * expf(-2.f * pb * pb * (t * t)) * cosf(TPI * fcs * t);
    }
    {
      const float fcs = 0.5f * (f3 + f4) * FS, bws = (f4 - f3) * FS;
      const float pb = PIF * bws;
      ir2[tid] = a2 * expf(-2.f * pb * pb * (t * t)) * cosf(TPI * fcs * t);
    }
  }
  __syncthreads();
  norm_pm1_shared(ir1, scratch, tid);
  norm_pm1_shared(ir2, scratch, tid);

  if (tid < FDIM) {
    const int i = tid;
    const int plo = (i - 125 > 0) ? (i - 125) : 0;
    const int phi = (i + 125 < 250) ? (i + 125) : 250;
    float s = 0.f;
    for (int p = plo; p <= phi; ++p) s += ir1[p] * ir2[p + 125 - i];
    casc[i] = s;
  }
  __syncthreads();
  norm_pm1_shared(casc, scratch, tid);

  if (tid < KPAD) {
    float v = 0.f;
    if (tid < FDIM) {
      const float win = 0.54f - 0.46f * cosf(TPI * ((float)tid / 250.f));
      v = casc[tid] * win;
    }
    Wbf[(size_t)f * KPAD + tid] = f2bf(v);
  }
}

// ---------------------------------------------------------------------------
// Implicit-GEMM conv, round-13: r7/r11 compute + LDS out-tile with
// ROW-SEQUENTIAL BURST epilogue (fillBuffer-mimicking write stream).
// Theory: conv is pinned at ~3 TB/s effective writes because ~16K concurrent
// 64-256B write frontiers (1024 resident blocks x 16 rows) thrash DRAM pages
// via L2 eviction order. Here: per half (16 f x 512 t) waves deposit D into
// an LDS tile (stride 516 -> <=2-way banks), then each wave streams 4 f-rows
// as 512B-contiguous dwordx2 instrs -> ~4 frontiers/block x 768 resident
// (3 blocks/CU, LDS 53.8KB) ~ 3K bursting frontiers, 5x fewer.
// Barriers are lgkm-only (r5-validated asm) -> store queue never drained.
// Same products, same chunk order -> bit-identical output (absmax 0.125).
// ---------------------------------------------------------------------------
__global__ __launch_bounds__(256, 3) void conv_mfma_kernel(
    const float* __restrict__ xin, const unsigned short* __restrict__ Wbf,
    float* __restrict__ outp) {
  __shared__ __align__(16) unsigned int xs[XSTOT];
  __shared__ __align__(16) float tile[16 * TS];      // 33 KB half-tile
  const int tid = threadIdx.x;
  const int n0  = blockIdx.x * NCHUNK;
  const int ft  = blockIdx.y;
  const int b   = blockIdx.z;
  const int l   = tid & 63, w = tid >> 6;
  const int m   = l & 15, h = l >> 4;

  // ---- stage x as 8 shifted bf16-pair copies: C_j[i] = (x[2i+j], x[2i+j+1]) ----
  const float* xg = xin + (size_t)b * T_IN;
  for (int i = tid; i < CPYLEN - 4; i += 256) {
    float e[10];
    #pragma unroll
    for (int q = 0; q < 10; ++q) {
      const int g = n0 + 2 * i + q;
      e[q] = (g < T_IN) ? xg[g] : 0.f;
    }
    #pragma unroll
    for (int j = 0; j < 8; ++j)
      xs[j * CPYLEN + i] = packbf(e[j], e[j + 1]);
  }

  // ---- W fragments (A-operand): lane row = m -> W[ft*16+m][k=8h+j+32c] ----
  const short* Wp = (const short*)Wbf;
  bf16x8 afr[8];
  #pragma unroll
  for (int c = 0; c < 8; ++c)
    afr[c] = *(const bf16x8*)(Wp + (ft * 16 + m) * KPAD + c * 32 + h * 8);

  __syncthreads();

  // lane-constant B(x) addressing (validated r4-r12):
  // tile at t_loc, chunk c -> copy m&7, 16B-unit index t_loc/8 + lane_q + 4c
  const unsigned int* psrc = xs + (m & 7) * CPYLEN;
  const int lane_q = h + (m >> 3);
  const size_t rowbase = ((size_t)b * NFILT + ft * 16) * T_OUT;

  #pragma unroll
  for (int hp = 0; hp < 2; ++hp) {               // two 512-t halves
    // ---- compute phase: wave w owns t in [hp*512 + w*128, +128) ----
    #pragma unroll
    for (int u = 0; u < 4; ++u) {                // pairs of 16-t tiles, 2 chains
      const int tl = w * 128 + u * 32;           // t within half
      const int qA = ((hp * 512 + tl) >> 3) + lane_q;
      f32x4 accA = (f32x4){0.f, 0.f, 0.f, 0.f};
      f32x4 accB = (f32x4){0.f, 0.f, 0.f, 0.f};

      #pragma unroll
      for (int c = 0; c < 8; ++c) {
        const bf16x8 xa = *(const bf16x8*)(psrc + 4 * (qA + 4 * c));
        const bf16x8 xb = *(const bf16x8*)(psrc + 4 * (qA + 2 + 4 * c));
        accA = __builtin_amdgcn_mfma_f32_16x16x32_bf16(afr[c], xa, accA, 0, 0, 0);
        accB = __builtin_amdgcn_mfma_f32_16x16x32_bf16(afr[c], xb, accB, 0, 0, 0);
      }

      // deposit D tile: row f' = 4h + r, col t = tl + m (A) / +16 (B)
      #pragma unroll
      for (int r = 0; r < 4; ++r) {
        tile[(4 * h + r) * TS + tl + m]      = accA[r];
        tile[(4 * h + r) * TS + tl + 16 + m] = accB[r];
      }
    }

    // all deposits visible before epilogue reads (lgkm-only: no vmcnt drain)
    asm volatile("s_waitcnt lgkmcnt(0)\n\ts_barrier" ::: "memory");

    // ---- epilogue: wave w streams rows 4w..4w+3; 512B-contiguous dwordx2 ----
    const int t0 = n0 + hp * 512;
    #pragma unroll
    for (int q = 0; q < 4; ++q) {
      const int fr = 4 * w + q;
      const size_t rb = rowbase + (size_t)fr * T_OUT;
      #pragma unroll
      for (int part = 0; part < 4; ++part) {     // 4 x 128-t contiguous pieces
        const int tloc = part * 128 + 2 * l;
        const float2 v = *(const float2*)&tile[fr * TS + tloc];
        const int tg = t0 + tloc;
        if (tg + 2 <= T_OUT) {
          *(float2*)&outp[rb + tg] = v;
        } else {
          if (tg < T_OUT)     outp[rb + tg]     = v.x;
          if (tg + 1 < T_OUT) outp[rb + tg + 1] = v.y;
        }
      }
    }

    // epilogue reads done before next half's deposits overwrite the tile
    asm volatile("s_waitcnt lgkmcnt(0)\n\ts_barrier" ::: "memory");
  }
}

// ---------------------------------------------------------------------------
extern "C" void kernel_launch(void* const* d_in, const int* in_sizes, int n_in,
                              void* d_out, int out_size, void* d_ws, size_t ws_size,
                              hipStream_t stream) {
  const float* x    = (const float*)d_in[0];
  const float* nf1  = (const float*)d_in[1];
  const float* nf2  = (const float*)d_in[2];
  const float* nf3  = (const float*)d_in[3];
  const float* nf4  = (const float*)d_in[4];
  const float* amp1 = (const float*)d_in[5];
  const float* amp2 = (const float*)d_in[6];
  unsigned short* Wbf = (unsigned short*)d_ws;   // 80*256*2 = 40 KB scratch
  float* out = (float*)d_out;

  build_filters_kernel<<<NFILT, 256, 0, stream>>>(nf1, nf2, nf3, nf4, amp1, amp2, Wbf);

  dim3 grid((T_OUT + NCHUNK - 1) / NCHUNK, NFT, 8);   // 63 x 5 x 8
  conv_mfma_kernel<<<grid, 256, 0, stream>>>(x, Wbf, out);
}

// Round 14
// 63.647 us; speedup vs baseline: 1.0179x; 1.0179x over previous
//
#include <hip/hip_runtime.h>

#define FDIM   251
#define NFILT  80
#define KPAD   256        // K padded to 8 chunks of 32 (zeros past 250)
#define T_IN   64000
#define T_OUT  63750      // 64000 - 251 + 1
#define NCHUNK 512        // output positions per block; wave owns contiguous 128
#define NFT    5          // filter tiles (16 filters each)
#define NXB    125        // t-chunks = ceil(T_OUT / NCHUNK)
#define CPYLEN 392        // dwords per shifted copy; 392 % 32 == 8 -> bank stagger
#define XSTOT  (8 * CPYLEN)   // 12.25 KB LDS

typedef short bf16x8 __attribute__((ext_vector_type(8)));
typedef float f32x4  __attribute__((ext_vector_type(4)));

__device__ __forceinline__ unsigned short f2bf(float f) {
  unsigned int u = __float_as_uint(f);
  unsigned int r = (u + 0x7fffu + ((u >> 16) & 1u)) >> 16;   // RNE
  return (unsigned short)r;
}
__device__ __forceinline__ unsigned int packbf(float a, float b) {
  return (unsigned int)f2bf(a) | ((unsigned int)f2bf(b) << 16);
}

// ---------------------------------------------------------------------------
// Filter construction (validated rounds 1-13). Emits bf16 W[80][256].
// ---------------------------------------------------------------------------
__device__ __forceinline__ void norm_pm1_shared(float* a, float* scratch, int tid) {
  float v  = (tid < FDIM) ? a[tid] : 0.f;
  float mn = (tid < FDIM) ? v : 1e30f;
  float mx = (tid < FDIM) ? v : -1e30f;
  #pragma unroll
  for (int o = 32; o > 0; o >>= 1) {
    mn = fminf(mn, __shfl_down(mn, o));
    mx = fmaxf(mx, __shfl_down(mx, o));
  }
  const int wid = tid >> 6;
  if ((tid & 63) == 0) { scratch[wid] = mn; scratch[4 + wid] = mx; }
  __syncthreads();
  if (tid == 0) {
    scratch[0] = fminf(fminf(scratch[0], scratch[1]), fminf(scratch[2], scratch[3]));
    scratch[4] = fmaxf(fmaxf(scratch[4], scratch[5]), fmaxf(scratch[6], scratch[7]));
  }
  __syncthreads();
  const float gmn = scratch[0], gmx = scratch[4];
  const float nv = 2.f * (v - gmn) / (gmx - gmn + 1e-6f) - 1.f;
  __syncthreads();
  float s = (tid < FDIM) ? nv : 0.f;
  #pragma unroll
  for (int o = 32; o > 0; o >>= 1) s += __shfl_down(s, o);
  if ((tid & 63) == 0) scratch[wid] = s;
  __syncthreads();
  if (tid == 0) scratch[0] = (scratch[0] + scratch[1] + scratch[2] + scratch[3]) / 251.f;
  __syncthreads();
  const float mean = scratch[0];
  if (tid < FDIM) a[tid] = nv - mean;
  __syncthreads();
}

__global__ __launch_bounds__(256) void build_filters_kernel(
    const float* __restrict__ nf1, const float* __restrict__ nf2,
    const float* __restrict__ nf3, const float* __restrict__ nf4,
    const float* __restrict__ amp1, const float* __restrict__ amp2,
    unsigned short* __restrict__ Wbf) {
  __shared__ float ir1[FDIM], ir2[FDIM], casc[FDIM];
  __shared__ float scratch[8];
  const int f = blockIdx.x, tid = threadIdx.x;
  const float FS  = 16000.f;
  const float MF  = 50.f / 16000.f;
  const float PIF = 3.14159265358979323846f;
  const float TPI = 6.28318530717958647692f;

  const float f1 = fminf(fmaxf(fabsf(nf1[f]) + MF, 0.f), 0.5f);
  const float f2 = fminf(fmaxf(f1 + fabsf(nf2[f] - f1) + MF, 0.f), 0.5f);
  const float f3 = fminf(fmaxf(fabsf(nf3[f]) + MF, 0.f), 0.5f);
  const float f4 = fminf(fmaxf(f3 + fabsf(nf4[f] - f3) + MF, 0.f), 0.5f);
  const float a1 = fabsf(amp1[f]);
  const float a2 = fabsf(amp2[f]);

  if (tid < FDIM) {
    const float t = (float)(tid + 1) / FS;
    {
      const float fcs = 0.5f * (f1 + f2) * FS, bws = (f2 - f1) * FS;
      const float pb = PIF * bws;
      ir1[tid] = a1 * expf(-2.f * pb * pb * (t * t)) * cosf(TPI * fcs * t);
    }
    {
      const float fcs = 0.5f * (f3 + f4) * FS, bws = (f4 - f3) * FS;
      const float pb = PIF * bws;
      ir2[tid] = a2 * expf(-2.f * pb * pb * (t * t)) * cosf(TPI * fcs * t);
    }
  }
  __syncthreads();
  norm_pm1_shared(ir1, scratch, tid);
  norm_pm1_shared(ir2, scratch, tid);

  if (tid < FDIM) {
    const int i = tid;
    const int plo = (i - 125 > 0) ? (i - 125) : 0;
    const int phi = (i + 125 < 250) ? (i + 125) : 250;
    float s = 0.f;
    for (int p = plo; p <= phi; ++p) s += ir1[p] * ir2[p + 125 - i];
    casc[i] = s;
  }
  __syncthreads();
  norm_pm1_shared(casc, scratch, tid);

  if (tid < KPAD) {
    float v = 0.f;
    if (tid < FDIM) {
      const float win = 0.54f - 0.46f * cosf(TPI * ((float)tid / 250.f));
      v = casc[tid] * win;
    }
    Wbf[(size_t)f * KPAD + tid] = f2bf(v);
  }
}

// ---------------------------------------------------------------------------
// Implicit-GEMM conv, round-14: r7 compute verbatim at HALF CHUNK + higher
// occupancy + bijective XCD-chunked swizzle.
//  - NCHUNK 512, 5000 blocks, __launch_bounds__(256,5) -> 1280 slots,
//    T_block ~12 us: async model 5000*12/1280 ~ 47 us (r12 tested this
//    confounded with a broken store orientation; here store = r7's 64B
//    full-line row pieces).
//  - XCD swizzle (m204 bijective, 125 = 8*15+5): XCD k owns ~16 CONSECUTIVE
//    t-chunks per (ft,b) -> its L2 dirty set per row is 32KB contiguous
//    (vs 2KB round-robin) -> longer HBM write bursts at eviction.
// Fragment addressing validated r4-r13; same products, same chunk order ->
// bit-identical output (absmax 0.125).
// ---------------------------------------------------------------------------
__global__ __launch_bounds__(256, 5) void conv_mfma_kernel(
    const float* __restrict__ xin, const unsigned short* __restrict__ Wbf,
    float* __restrict__ outp) {
  __shared__ __align__(16) unsigned int xs[XSTOT];
  const int tid = threadIdx.x;

  // bijective XCD-chunked swizzle of the t-chunk index (q=15, r=5)
  {
  }
  const int orig = blockIdx.x;
  const int xcd  = orig & 7;
  const int pos  = orig >> 3;
  const int start = (xcd < 5) ? xcd * 16 : 5 * 16 + (xcd - 5) * 15;
  const int gx = start + pos;                  // swizzled t-chunk in [0,125)

  const int n0  = gx * NCHUNK;
  const int ft  = blockIdx.y;
  const int b   = blockIdx.z;
  const int l   = tid & 63, w = tid >> 6;
  const int m   = l & 15, h = l >> 4;

  // ---- stage x as 8 shifted bf16-pair copies: C_j[i] = (x[2i+j], x[2i+j+1]) ----
  const float* xg = xin + (size_t)b * T_IN;
  for (int i = tid; i < CPYLEN - 4; i += 256) {
    float e[10];
    #pragma unroll
    for (int q = 0; q < 10; ++q) {
      const int g = n0 + 2 * i + q;
      e[q] = (g < T_IN) ? xg[g] : 0.f;
    }
    #pragma unroll
    for (int j = 0; j < 8; ++j)
      xs[j * CPYLEN + i] = packbf(e[j], e[j + 1]);
  }

  // ---- W fragments (A-operand): lane row = m -> W[ft*16+m][k=8h+j+32c] ----
  const short* Wp = (const short*)Wbf;
  bf16x8 afr[8];
  #pragma unroll
  for (int c = 0; c < 8; ++c)
    afr[c] = *(const bf16x8*)(Wp + (ft * 16 + m) * KPAD + c * 32 + h * 8);

  __syncthreads();

  // lane-constant B(x) addressing (validated r4-r13):
  // tile at t_loc, chunk c -> copy m&7, 16B-unit index t_loc/8 + lane_q + 4c
  const unsigned int* psrc = xs + (m & 7) * CPYLEN;
  const int lane_q = h + (m >> 3);
  const int tw0 = w * 128;                     // wave's local t base (8 tiles)
  const size_t rowh = ((size_t)b * NFILT + ft * 16 + 4 * h) * T_OUT;

  for (int jp = 0; jp < 4; ++jp) {             // 4 pairs of 16-t tiles, 2 chains
    const int qA = ((tw0 + jp * 32) >> 3) + lane_q;
    f32x4 accA = (f32x4){0.f, 0.f, 0.f, 0.f};
    f32x4 accB = (f32x4){0.f, 0.f, 0.f, 0.f};

    #pragma unroll
    for (int c = 0; c < 8; ++c) {
      const bf16x8 xa = *(const bf16x8*)(psrc + 4 * (qA + 4 * c));
      const bf16x8 xb = *(const bf16x8*)(psrc + 4 * (qA + 2 + 4 * c));
      accA = __builtin_amdgcn_mfma_f32_16x16x32_bf16(afr[c], xa, accA, 0, 0, 0);
      accB = __builtin_amdgcn_mfma_f32_16x16x32_bf16(afr[c], xb, accB, 0, 0, 0);
    }

    const int tgA = n0 + tw0 + jp * 32 + m;    // D col = m
    const int tgB = tgA + 16;
    #pragma unroll
    for (int r = 0; r < 4; ++r) {              // D row = 4h + r
      const size_t rb = rowh + (size_t)r * T_OUT;
      if (tgA < T_OUT) outp[rb + tgA] = accA[r];
      if (tgB < T_OUT) outp[rb + tgB] = accB[r];
    }
  }
}

// ---------------------------------------------------------------------------
extern "C" void kernel_launch(void* const* d_in, const int* in_sizes, int n_in,
                              void* d_out, int out_size, void* d_ws, size_t ws_size,
                              hipStream_t stream) {
  const float* x    = (const float*)d_in[0];
  const float* nf1  = (const float*)d_in[1];
  const float* nf2  = (const float*)d_in[2];
  const float* nf3  = (const float*)d_in[3];
  const float* nf4  = (const float*)d_in[4];
  const float* amp1 = (const float*)d_in[5];
  const float* amp2 = (const float*)d_in[6];
  unsigned short* Wbf = (unsigned short*)d_ws;   // 80*256*2 = 40 KB scratch
  float* out = (float*)d_out;

  build_filters_kernel<<<NFILT, 256, 0, stream>>>(nf1, nf2, nf3, nf4, amp1, amp2, Wbf);

  dim3 grid(NXB, NFT, 8);   // 125 x 5 x 8 = 5000 blocks
  conv_mfma_kernel<<<grid, 256, 0, stream>>>(x, Wbf, out);
}